// Round 1
// baseline (1477.592 us; speedup 1.0000x reference)
//
#include <hip/hip_runtime.h>
#include <math.h>

#define SEQ 256
#define BATCH 512
#define IN_DIM 512
#define HID 512
#define NQ 32

__device__ __forceinline__ float fast_rcp(float x) { return __builtin_amdgcn_rcpf(x); }

__device__ __forceinline__ float tanh_fast(float x) {
    // tanh(x) = sign(x) * (1 - e) / (1 + e),  e = exp(-2|x|)  (never overflows)
    float a = fabsf(x);
    float e = __expf(-2.0f * a);
    float r = (1.0f - e) * fast_rcp(1.0f + e);
    return copysignf(r, x);
}

// ---------------------------------------------------------------------------
// Phase 1: Xp[row][nq] = fc_b[nq] + sum_k inputs[row][k] * fc_w[nq][k]
// row = t*BATCH + b, k in [0,512).  Grid 2048 x 256, 64 rows per block.
// Thread layout: g = tid>>3 (the nq it owns), s = tid&7, k = s*64 + j.
// Wx chunk (64 floats) lives in registers; reduce over 8 lanes via shfl.
// ---------------------------------------------------------------------------
__global__ __launch_bounds__(256) void xp_kernel(const float* __restrict__ x,
                                                 const float* __restrict__ fc_w,
                                                 const float* __restrict__ fc_b,
                                                 float* __restrict__ xp) {
    const int tid = threadIdx.x;
    const int g = tid >> 3;   // nq index 0..31
    const int s = tid & 7;    // k-chunk 0..7

    float w[64];
    const float* wrow = fc_w + (size_t)g * (IN_DIM + HID) + s * 64;
#pragma unroll
    for (int j4 = 0; j4 < 16; ++j4) {
        float4 v = reinterpret_cast<const float4*>(wrow)[j4];
        w[j4 * 4 + 0] = v.x; w[j4 * 4 + 1] = v.y;
        w[j4 * 4 + 2] = v.z; w[j4 * 4 + 3] = v.w;
    }
    const float bias = fc_b[g];

    const int row0 = blockIdx.x * 64;
    for (int r = 0; r < 64; ++r) {
        const float* xr = x + (size_t)(row0 + r) * IN_DIM + s * 64;
        float acc = 0.0f;
#pragma unroll
        for (int j4 = 0; j4 < 16; ++j4) {
            float4 v = reinterpret_cast<const float4*>(xr)[j4];
            acc += v.x * w[j4 * 4 + 0];
            acc += v.y * w[j4 * 4 + 1];
            acc += v.z * w[j4 * 4 + 2];
            acc += v.w * w[j4 * 4 + 3];
        }
        acc += __shfl_xor(acc, 1);
        acc += __shfl_xor(acc, 2);
        acc += __shfl_xor(acc, 4);
        if (s == 0) xp[(size_t)(row0 + r) * NQ + g] = acc + bias;
    }
}

// ---------------------------------------------------------------------------
// Phase 2: per-batch recurrence. 512 blocks (one per batch), 256 threads.
// Thread layout for h-GEMV: g = tid>>5 owns nq = 4g..4g+3; s = tid&31, k = s+32j.
//   -> h_lds[s+32j] bank = s : conflict-free, broadcast across the 8 g-groups.
// Phase C: thread owns hid = tid and tid+256; out_w rows in registers.
// ---------------------------------------------------------------------------
__global__ __launch_bounds__(256, 2) void rnn_kernel(const float* __restrict__ xp,
                                                     const float* __restrict__ fc_w,
                                                     const float* __restrict__ out_w,
                                                     const float* __restrict__ out_b,
                                                     float* __restrict__ out) {
    const int b = blockIdx.x;
    const int tid = threadIdx.x;
    const int g = tid >> 5;   // 0..7
    const int s = tid & 31;   // 0..31

    __shared__ __align__(16) float h_lds[HID];
    __shared__ __align__(16) float qin_s[NQ];
    __shared__ __align__(16) float sig_s[NQ];
    __shared__ __align__(16) float th_s[NQ];

    // Wh fragment: wh[i][j] = fc_w[4g+i][512 + s + 32j]
    float wh[4][16];
#pragma unroll
    for (int i = 0; i < 4; ++i) {
        const float* wr = fc_w + (size_t)(g * 4 + i) * (IN_DIM + HID) + IN_DIM + s;
#pragma unroll
        for (int j = 0; j < 16; ++j) wh[i][j] = wr[32 * j];
    }
    // out_w fragments for hid = tid and tid+256
    float ow[2][32];
#pragma unroll
    for (int p = 0; p < 2; ++p) {
        const float* owr = out_w + (size_t)(tid + p * 256) * NQ;
#pragma unroll
        for (int q4 = 0; q4 < 8; ++q4) {
            float4 v = reinterpret_cast<const float4*>(owr)[q4];
            ow[p][q4 * 4 + 0] = v.x; ow[p][q4 * 4 + 1] = v.y;
            ow[p][q4 * 4 + 2] = v.z; ow[p][q4 * 4 + 3] = v.w;
        }
    }
    const float ob0 = out_b[tid];
    const float ob1 = out_b[tid + 256];

    h_lds[tid] = 0.0f;
    h_lds[tid + 256] = 0.0f;
    float c0 = 0.0f, c1 = 0.0f;
    __syncthreads();

    const float* xpb = xp + (size_t)b * NQ;
    float* outb = out + (size_t)b * HID;
    float* hx_out = out + (size_t)SEQ * BATCH * HID + (size_t)b * HID;
    float* cx_out = hx_out + (size_t)BATCH * HID;

    for (int t = 0; t < SEQ; ++t) {
        // ---- Phase A: q_in = Xp[t,b,:] + h @ Wh.T -------------------------
        float4 xpv = make_float4(0.f, 0.f, 0.f, 0.f);
        if (s == 0)
            xpv = reinterpret_cast<const float4*>(xpb + (size_t)t * BATCH * NQ)[g];
        float a0 = 0.f, a1 = 0.f, a2 = 0.f, a3 = 0.f;
#pragma unroll
        for (int j = 0; j < 16; ++j) {
            float hv = h_lds[s + 32 * j];
            a0 += hv * wh[0][j];
            a1 += hv * wh[1][j];
            a2 += hv * wh[2][j];
            a3 += hv * wh[3][j];
        }
#pragma unroll
        for (int m = 1; m <= 16; m <<= 1) {
            a0 += __shfl_xor(a0, m);
            a1 += __shfl_xor(a1, m);
            a2 += __shfl_xor(a2, m);
            a3 += __shfl_xor(a3, m);
        }
        if (s == 0) {
            qin_s[g * 4 + 0] = a0 + xpv.x;
            qin_s[g * 4 + 1] = a1 + xpv.y;
            qin_s[g * 4 + 2] = a2 + xpv.z;
            qin_s[g * 4 + 3] = a3 + xpv.w;
        }
        __syncthreads();

        // ---- Phase B: quantum gate + activations (wave 0, lanes 0..31) ----
        if (tid < 32) {
            float q = qin_s[tid];
            float p = __cosf(q);
#pragma unroll
            for (int off = 1; off <= 16; off <<= 1) {
                float up = __shfl_up(p, off, 32);
                if (tid >= off) p *= up;
            }
            float es = __expf(-p);
            sig_s[tid] = fast_rcp(1.0f + es);
            float e2 = __expf(-2.0f * p);
            th_s[tid] = (1.0f - e2) * fast_rcp(1.0f + e2);
        }
        __syncthreads();

        // ---- Phase C: f/g GEMV + state update -----------------------------
        float f0 = ob0, f1 = ob1, g0 = ob0, g1 = ob1;
#pragma unroll
        for (int q4 = 0; q4 < 8; ++q4) {
            float4 sv = reinterpret_cast<const float4*>(sig_s)[q4];
            float4 tv = reinterpret_cast<const float4*>(th_s)[q4];
            f0 += sv.x * ow[0][q4 * 4 + 0] + sv.y * ow[0][q4 * 4 + 1]
                + sv.z * ow[0][q4 * 4 + 2] + sv.w * ow[0][q4 * 4 + 3];
            f1 += sv.x * ow[1][q4 * 4 + 0] + sv.y * ow[1][q4 * 4 + 1]
                + sv.z * ow[1][q4 * 4 + 2] + sv.w * ow[1][q4 * 4 + 3];
            g0 += tv.x * ow[0][q4 * 4 + 0] + tv.y * ow[0][q4 * 4 + 1]
                + tv.z * ow[0][q4 * 4 + 2] + tv.w * ow[0][q4 * 4 + 3];
            g1 += tv.x * ow[1][q4 * 4 + 0] + tv.y * ow[1][q4 * 4 + 1]
                + tv.z * ow[1][q4 * 4 + 2] + tv.w * ow[1][q4 * 4 + 3];
        }
        c0 = f0 * (c0 + g0);           // f*c + i*g with i == f
        c1 = f1 * (c1 + g1);
        float h0 = f0 * tanh_fast(c0); // o == f
        float h1 = f1 * tanh_fast(c1);

        h_lds[tid] = h0;
        h_lds[tid + 256] = h1;
        float* orow = outb + (size_t)t * BATCH * HID;
        orow[tid] = h0;
        orow[tid + 256] = h1;
        if (t == SEQ - 1) {
            hx_out[tid] = h0; hx_out[tid + 256] = h1;
            cx_out[tid] = c0; cx_out[tid + 256] = c1;
        }
        __syncthreads();
    }
}

extern "C" void kernel_launch(void* const* d_in, const int* in_sizes, int n_in,
                              void* d_out, int out_size, void* d_ws, size_t ws_size,
                              hipStream_t stream) {
    const float* inputs = (const float*)d_in[0];
    const float* fc_w   = (const float*)d_in[1];
    const float* fc_b   = (const float*)d_in[2];
    const float* out_w  = (const float*)d_in[3];
    const float* out_b  = (const float*)d_in[4];
    float* out = (float*)d_out;
    float* xp  = (float*)d_ws;   // SEQ*BATCH*NQ floats = 16.8 MB

    xp_kernel<<<(SEQ * BATCH) / 64, 256, 0, stream>>>(inputs, fc_w, fc_b, xp);
    rnn_kernel<<<BATCH, 256, 0, stream>>>(xp, fc_w, out_w, out_b, out);
}

// Round 2
// 568.160 us; speedup vs baseline: 2.6007x; 2.6007x over previous
//
#include <hip/hip_runtime.h>
#include <math.h>

#define SEQ 256
#define BATCH 512
#define IN_DIM 512
#define HID 512
#define NQ 32

__device__ __forceinline__ float fast_rcp(float x) { return __builtin_amdgcn_rcpf(x); }

__device__ __forceinline__ float tanh_fast(float x) {
    // tanh(x) = sign(x) * (1 - e) / (1 + e),  e = exp(-2|x|)  (never overflows)
    float a = fabsf(x);
    float e = __expf(-2.0f * a);
    float r = (1.0f - e) * fast_rcp(1.0f + e);
    return copysignf(r, x);
}

// ---------------------------------------------------------------------------
// Phase 1: Xp[row][nq] = fc_b[nq] + sum_k inputs[row][k] * fc_w[nq][k]
// row = t*BATCH + b (131072 rows), k in [0,512).
// 4096 blocks x 256 threads; 32 rows per block staged in LDS (64 KB),
// loaded fully coalesced as float4.
// Thread (g2 = tid>>5, s = tid&31): owns nq = 4*g2..4*g2+3, k-slice
// {4s+128j : j=0..3} (16 k values, 4 float4s). w fragment = 16 float4 in
// registers -- __launch_bounds__(256,2) caps VGPR at 256 so it CANNOT spill
// (round-0 bug: VGPR capped at 40 -> w spilled to scratch -> 8.6 GB traffic).
// LDS read tile4[r*128 + s + 32j]: 32 consecutive float4 addrs x2 broadcast,
// conflict-free. Reduce over the 32 s-lanes via 5x shfl_xor.
// ---------------------------------------------------------------------------
__global__ __launch_bounds__(256, 2) void xp_kernel(const float* __restrict__ x,
                                                    const float* __restrict__ fc_w,
                                                    const float* __restrict__ fc_b,
                                                    float* __restrict__ xp) {
    const int tid = threadIdx.x;
    const int g2 = tid >> 5;  // 0..7 : nq group (owns nq 4*g2 .. 4*g2+3)
    const int s  = tid & 31;  // 0..31: k-split lane

    __shared__ float4 tile4[32 * 128];  // 32 rows x 512 floats = 64 KB

    // --- weight fragment: w4[i][j] = fc_w[4*g2+i][4s+128j .. +3] -----------
    float4 w4[4][4];
#pragma unroll
    for (int i = 0; i < 4; ++i) {
        const float* wr = fc_w + (size_t)(g2 * 4 + i) * (IN_DIM + HID);
#pragma unroll
        for (int j = 0; j < 4; ++j)
            w4[i][j] = *reinterpret_cast<const float4*>(wr + 4 * s + 128 * j);
    }
    const float4 bias4 = reinterpret_cast<const float4*>(fc_b)[g2];

    // --- coalesced tile load: 4096 float4s, 16 per thread ------------------
    const float4* x4 = reinterpret_cast<const float4*>(x) + (size_t)blockIdx.x * (32 * 128);
#pragma unroll
    for (int q = 0; q < 16; ++q)
        tile4[tid + 256 * q] = x4[tid + 256 * q];
    __syncthreads();

    // --- compute 32 rows ---------------------------------------------------
    const int row0 = blockIdx.x * 32;
    float4* xp4 = reinterpret_cast<float4*>(xp);
    for (int r = 0; r < 32; ++r) {
        float a0 = 0.f, a1 = 0.f, a2 = 0.f, a3 = 0.f;
#pragma unroll
        for (int j = 0; j < 4; ++j) {
            float4 xv = tile4[r * 128 + s + 32 * j];
            a0 += xv.x * w4[0][j].x + xv.y * w4[0][j].y + xv.z * w4[0][j].z + xv.w * w4[0][j].w;
            a1 += xv.x * w4[1][j].x + xv.y * w4[1][j].y + xv.z * w4[1][j].z + xv.w * w4[1][j].w;
            a2 += xv.x * w4[2][j].x + xv.y * w4[2][j].y + xv.z * w4[2][j].z + xv.w * w4[2][j].w;
            a3 += xv.x * w4[3][j].x + xv.y * w4[3][j].y + xv.z * w4[3][j].z + xv.w * w4[3][j].w;
        }
#pragma unroll
        for (int m = 1; m <= 16; m <<= 1) {
            a0 += __shfl_xor(a0, m);
            a1 += __shfl_xor(a1, m);
            a2 += __shfl_xor(a2, m);
            a3 += __shfl_xor(a3, m);
        }
        if (s == 0)
            xp4[(size_t)(row0 + r) * 8 + g2] =
                make_float4(a0 + bias4.x, a1 + bias4.y, a2 + bias4.z, a3 + bias4.w);
    }
}

// ---------------------------------------------------------------------------
// Phase 2: per-batch recurrence. 512 blocks (one per batch), 256 threads.
// Thread layout for h-GEMV: g = tid>>5 owns nq = 4g..4g+3; s = tid&31, k = s+32j.
//   -> h_lds[s+32j] bank = s : conflict-free, broadcast across the 8 g-groups.
// Phase C: thread owns hid = tid and tid+256; out_w rows in registers.
// ---------------------------------------------------------------------------
__global__ __launch_bounds__(256, 2) void rnn_kernel(const float* __restrict__ xp,
                                                     const float* __restrict__ fc_w,
                                                     const float* __restrict__ out_w,
                                                     const float* __restrict__ out_b,
                                                     float* __restrict__ out) {
    const int b = blockIdx.x;
    const int tid = threadIdx.x;
    const int g = tid >> 5;   // 0..7
    const int s = tid & 31;   // 0..31

    __shared__ __align__(16) float h_lds[HID];
    __shared__ __align__(16) float qin_s[NQ];
    __shared__ __align__(16) float sig_s[NQ];
    __shared__ __align__(16) float th_s[NQ];

    // Wh fragment: wh[i][j] = fc_w[4g+i][512 + s + 32j]
    float wh[4][16];
#pragma unroll
    for (int i = 0; i < 4; ++i) {
        const float* wr = fc_w + (size_t)(g * 4 + i) * (IN_DIM + HID) + IN_DIM + s;
#pragma unroll
        for (int j = 0; j < 16; ++j) wh[i][j] = wr[32 * j];
    }
    // out_w fragments for hid = tid and tid+256
    float ow[2][32];
#pragma unroll
    for (int p = 0; p < 2; ++p) {
        const float* owr = out_w + (size_t)(tid + p * 256) * NQ;
#pragma unroll
        for (int q4 = 0; q4 < 8; ++q4) {
            float4 v = reinterpret_cast<const float4*>(owr)[q4];
            ow[p][q4 * 4 + 0] = v.x; ow[p][q4 * 4 + 1] = v.y;
            ow[p][q4 * 4 + 2] = v.z; ow[p][q4 * 4 + 3] = v.w;
        }
    }
    const float ob0 = out_b[tid];
    const float ob1 = out_b[tid + 256];

    h_lds[tid] = 0.0f;
    h_lds[tid + 256] = 0.0f;
    float c0 = 0.0f, c1 = 0.0f;
    __syncthreads();

    const float* xpb = xp + (size_t)b * NQ;
    float* outb = out + (size_t)b * HID;
    float* hx_out = out + (size_t)SEQ * BATCH * HID + (size_t)b * HID;
    float* cx_out = hx_out + (size_t)BATCH * HID;

    for (int t = 0; t < SEQ; ++t) {
        // ---- Phase A: q_in = Xp[t,b,:] + h @ Wh.T -------------------------
        float4 xpv = make_float4(0.f, 0.f, 0.f, 0.f);
        if (s == 0)
            xpv = reinterpret_cast<const float4*>(xpb + (size_t)t * BATCH * NQ)[g];
        float a0 = 0.f, a1 = 0.f, a2 = 0.f, a3 = 0.f;
#pragma unroll
        for (int j = 0; j < 16; ++j) {
            float hv = h_lds[s + 32 * j];
            a0 += hv * wh[0][j];
            a1 += hv * wh[1][j];
            a2 += hv * wh[2][j];
            a3 += hv * wh[3][j];
        }
#pragma unroll
        for (int m = 1; m <= 16; m <<= 1) {
            a0 += __shfl_xor(a0, m);
            a1 += __shfl_xor(a1, m);
            a2 += __shfl_xor(a2, m);
            a3 += __shfl_xor(a3, m);
        }
        if (s == 0) {
            qin_s[g * 4 + 0] = a0 + xpv.x;
            qin_s[g * 4 + 1] = a1 + xpv.y;
            qin_s[g * 4 + 2] = a2 + xpv.z;
            qin_s[g * 4 + 3] = a3 + xpv.w;
        }
        __syncthreads();

        // ---- Phase B: quantum gate + activations (wave 0, lanes 0..31) ----
        if (tid < 32) {
            float q = qin_s[tid];
            float p = __cosf(q);
#pragma unroll
            for (int off = 1; off <= 16; off <<= 1) {
                float up = __shfl_up(p, off, 32);
                if (tid >= off) p *= up;
            }
            float es = __expf(-p);
            sig_s[tid] = fast_rcp(1.0f + es);
            float e2 = __expf(-2.0f * p);
            th_s[tid] = (1.0f - e2) * fast_rcp(1.0f + e2);
        }
        __syncthreads();

        // ---- Phase C: f/g GEMV + state update -----------------------------
        float f0 = ob0, f1 = ob1, g0 = ob0, g1 = ob1;
#pragma unroll
        for (int q4 = 0; q4 < 8; ++q4) {
            float4 sv = reinterpret_cast<const float4*>(sig_s)[q4];
            float4 tv = reinterpret_cast<const float4*>(th_s)[q4];
            f0 += sv.x * ow[0][q4 * 4 + 0] + sv.y * ow[0][q4 * 4 + 1]
                + sv.z * ow[0][q4 * 4 + 2] + sv.w * ow[0][q4 * 4 + 3];
            f1 += sv.x * ow[1][q4 * 4 + 0] + sv.y * ow[1][q4 * 4 + 1]
                + sv.z * ow[1][q4 * 4 + 2] + sv.w * ow[1][q4 * 4 + 3];
            g0 += tv.x * ow[0][q4 * 4 + 0] + tv.y * ow[0][q4 * 4 + 1]
                + tv.z * ow[0][q4 * 4 + 2] + tv.w * ow[0][q4 * 4 + 3];
            g1 += tv.x * ow[1][q4 * 4 + 0] + tv.y * ow[1][q4 * 4 + 1]
                + tv.z * ow[1][q4 * 4 + 2] + tv.w * ow[1][q4 * 4 + 3];
        }
        c0 = f0 * (c0 + g0);           // f*c + i*g with i == f
        c1 = f1 * (c1 + g1);
        float h0 = f0 * tanh_fast(c0); // o == f
        float h1 = f1 * tanh_fast(c1);

        h_lds[tid] = h0;
        h_lds[tid + 256] = h1;
        float* orow = outb + (size_t)t * BATCH * HID;
        orow[tid] = h0;
        orow[tid + 256] = h1;
        if (t == SEQ - 1) {
            hx_out[tid] = h0; hx_out[tid + 256] = h1;
            cx_out[tid] = c0; cx_out[tid + 256] = c1;
        }
        __syncthreads();
    }
}

extern "C" void kernel_launch(void* const* d_in, const int* in_sizes, int n_in,
                              void* d_out, int out_size, void* d_ws, size_t ws_size,
                              hipStream_t stream) {
    const float* inputs = (const float*)d_in[0];
    const float* fc_w   = (const float*)d_in[1];
    const float* fc_b   = (const float*)d_in[2];
    const float* out_w  = (const float*)d_in[3];
    const float* out_b  = (const float*)d_in[4];
    float* out = (float*)d_out;
    float* xp  = (float*)d_ws;   // SEQ*BATCH*NQ floats = 16.8 MB

    xp_kernel<<<(SEQ * BATCH) / 32, 256, 0, stream>>>(inputs, fc_w, fc_b, xp);
    rnn_kernel<<<BATCH, 256, 0, stream>>>(xp, fc_w, out_w, out_b, out);
}